// Round 6
// baseline (104.845 us; speedup 1.0000x reference)
//
#include <hip/hip_runtime.h>
#include <math.h>

#ifndef M_PI
#define M_PI 3.14159265358979323846
#endif

#define SAMPLES_PER_THREAD 8
#define FLAG_MAGIC 0x5a17c0deu

typedef float v2f __attribute__((ext_vector_type(2)));

__device__ __forceinline__ float rfl(float x)
{
    return __int_as_float(__builtin_amdgcn_readfirstlane(__float_as_int(x)));
}

// Real RY butterfly on bit with stride ST: (a,b) -> (c*a - s*b, s*a + c*b)
template <int ST>
__device__ __forceinline__ void rotF(float c, float s, float (&vr)[8], float (&vi)[8])
{
#pragma unroll
    for (int k = 0; k < 8; ++k) {
        if (k & ST) continue;
        const int k1 = k + ST;
        const float ar = vr[k],  ai = vi[k];
        const float br = vr[k1], bi = vi[k1];
        vr[k]  = c * ar - s * br;  vi[k]  = c * ai - s * bi;
        vr[k1] = s * ar + c * br;  vi[k1] = s * ai + c * bi;
    }
}

// ---------------------------------------------------------------------------
// Block-local coefficient build (R5 prep, as a function). ALL 256 threads of
// the block must call this (contains __syncthreads). Fills sC[0..25] with
// {a_k, b_k}: out(theta) = sum_k a_k cos(k theta) + b_k sin(k theta),
// theta = pi*t/2. Exact: degree 24 < 32 = Nyquist of the 64-point sampling.
// ---------------------------------------------------------------------------
__device__ void build_coeffs(const float* __restrict__ theta,
                             float2* sU, float* sOut, float2* sCis, float2* sC)
{
    const int tid = threadIdx.x;

    // ---- 1) three 8x8 ansatz-layer matrices (lanes 0..23) ----
    if (tid < 24) {
        const int l = tid >> 3;
        const int c = tid & 7;
        float re[8], im[8];
#pragma unroll
        for (int k = 0; k < 8; ++k) { re[k] = (k == c) ? 1.f : 0.f; im[k] = 0.f; }

#pragma unroll
        for (int q = 0; q < 3; ++q) {
            const int p  = 2 - q;
            const int st = 1 << p;
            const float a0 = theta[l * 9 + q * 3 + 0];
            const float a1 = theta[l * 9 + q * 3 + 1];
            const float a2 = theta[l * 9 + q * 3 + 2];
            float sz, cz, sx, cx, sz2, cz2;
            __sincosf(0.5f * a0, &sz,  &cz);
            __sincosf(0.5f * a1, &sx,  &cx);
            __sincosf(0.5f * a2, &sz2, &cz2);
#pragma unroll
            for (int k = 0; k < 8; ++k) {          // RZ(a0)
                const float s = ((k >> p) & 1) ? sz : -sz;
                const float r0 = re[k] * cz - im[k] * s;
                const float i0 = re[k] * s  + im[k] * cz;
                re[k] = r0; im[k] = i0;
            }
#pragma unroll
            for (int k = 0; k < 8; ++k) {          // RX(a1)
                if ((k >> p) & 1) continue;
                const int k1 = k + st;
                const float r0 =  cx * re[k]  + sx * im[k1];
                const float i0 =  cx * im[k]  - sx * re[k1];
                const float r1 =  sx * im[k]  + cx * re[k1];
                const float i1 = -sx * re[k]  + cx * im[k1];
                re[k] = r0; im[k] = i0; re[k1] = r1; im[k1] = i1;
            }
#pragma unroll
            for (int k = 0; k < 8; ++k) {          // RZ(a2)
                const float s = ((k >> p) & 1) ? sz2 : -sz2;
                const float r0 = re[k] * cz2 - im[k] * s;
                const float i0 = re[k] * s   + im[k] * cz2;
                re[k] = r0; im[k] = i0;
            }
        }
        // CNOT(0,1), CNOT(1,2), CNOT(2,0)
#define SWP(a, b) { float tr = re[a]; re[a] = re[b]; re[b] = tr; \
                    float ti = im[a]; im[a] = im[b]; im[b] = ti; }
        SWP(4, 6); SWP(5, 7);
        SWP(2, 3); SWP(6, 7);
        SWP(1, 5); SWP(3, 7);
#undef SWP
#pragma unroll
        for (int r = 0; r < 8; ++r)
            sU[l * 64 + r * 8 + c] = make_float2(re[r], im[r]);
    }
    __syncthreads();

    // ---- 2) circuit eval at theta_j = 2*pi*j/64, j = lane (wave 0) ----
    if (tid < 64) {
        const float w0 = (float)(M_PI / 32.0);
        float c1, s1;
        __sincosf(w0 * (float)tid, &s1, &c1);
        const float c2 = c1 * c1 - s1 * s1, s2 = 2.f * s1 * c1;
        const float c3 = c2 * c1 - s2 * s1, s3 = s2 * c1 + c2 * s1;

        float wr[8], wi[8];
#pragma unroll
        for (int r = 0; r < 8; ++r) { const float2 u = sU[r * 8]; wr[r] = u.x; wi[r] = u.y; }
        rotF<4>(c1, s1, wr, wi);
        rotF<2>(c2, s2, wr, wi);
        rotF<1>(c3, s3, wr, wi);

        float xr[8], xi[8];
#pragma unroll
        for (int r = 0; r < 8; ++r) {
            float zr = 0.f, zi = 0.f;
#pragma unroll
            for (int cc = 0; cc < 8; ++cc) {
                const float2 u = sU[64 + r * 8 + cc];
                zr += u.x * wr[cc] - u.y * wi[cc];
                zi += u.x * wi[cc] + u.y * wr[cc];
            }
            xr[r] = zr; xi[r] = zi;
        }
        rotF<4>(c1, s1, xr, xi);
        rotF<2>(c2, s2, xr, xi);
        rotF<1>(c3, s3, xr, xi);

        float v = 0.f;
#pragma unroll
        for (int r = 0; r < 8; ++r) {
            float zr = 0.f, zi = 0.f;
#pragma unroll
            for (int cc = 0; cc < 8; ++cc) {
                const float2 u = sU[128 + r * 8 + cc];
                zr += u.x * xr[cc] - u.y * xi[cc];
                zi += u.x * xi[cc] + u.y * xr[cc];
            }
            const float m = zr * zr + zi * zi;
            v += (r < 4) ? m : -m;
        }
        sOut[tid] = v;
        sCis[tid] = make_float2(c1, s1);
    }
    __syncthreads();

    // ---- 3) trig-free 64-point DFT: lane k sums v_j * cis(k*theta_j) ----
    if (tid < 26) {
        if (tid == 25) {
            sC[25] = make_float2(0.f, 0.f);
        } else {
            float sa = 0.f, sb = 0.f;
#pragma unroll
            for (int j = 0; j < 64; ++j) {
                const float  vj = sOut[j];
                const float2 w  = sCis[(tid * j) & 63];
                sa += vj * w.x;
                sb += vj * w.y;
            }
            const float sc = (tid == 0) ? (1.f / 64.f) : (2.f / 64.f);
            sC[tid] = make_float2(sa * sc, (tid == 0) ? 0.f : sb * sc);
        }
    }
    __syncthreads();
}

// Packed-FP32 Chebyshev series eval, AB[k] = {a_k, b_k} wave-uniform.
__device__ __forceinline__ float evalSeries(float tval, const v2f (&AB)[25])
{
    const float th = 1.5707963267948966f * tval;   // theta = pi*t/2
    float s1, c1;
    __sincosf(th, &s1, &c1);
    const v2f tc = { 2.f * c1, 2.f * c1 };
    v2f pp = { 1.f, 0.f };        // cis(0)
    v2f pc = { c1, s1 };          // cis(theta)
    v2f acc = AB[0] * pp + AB[1] * pc;
#pragma unroll
    for (int k = 2; k <= 24; ++k) {
        const v2f pn = tc * pc - pp;   // cis(k*theta) via Chebyshev
        pp = pc; pc = pn;
        acc = AB[k] * pn + acc;
    }
    return acc.x + acc.y;
}

// ---------------------------------------------------------------------------
// Fused kernel. Block 0 builds coefficients and publishes them through d_ws
// (poisoned to 0xAA by the harness before every launch -> flag auto-rearmed).
// Other blocks bounded-spin on the flag; on (pathological) timeout they fall
// back to block-local coefficient build, so termination never depends on
// dispatch order or co-residency.
// ---------------------------------------------------------------------------
__global__ __launch_bounds__(256, 4)
void qb_fused(const float* __restrict__ t, const float* __restrict__ theta,
              float* __restrict__ out, int n, unsigned int* __restrict__ ws)
{
    __shared__ float2 sU[192];
    __shared__ float  sOut[64];
    __shared__ float2 sCis[64];
    __shared__ __align__(16) float2 sC[26];
    __shared__ int sState;

    const int tid  = threadIdx.x;
    const int base = (blockIdx.x * 256 + tid) * SAMPLES_PER_THREAD;
    const bool full = (base + SAMPLES_PER_THREAD - 1 < n);

    // Issue t-loads immediately: their HBM latency/streaming overlaps the
    // coefficient wait below.
    float4 tv0, tv1;
    if (full) {
        tv0 = *reinterpret_cast<const float4*>(t + base);
        tv1 = *reinterpret_cast<const float4*>(t + base + 4);
    }

    unsigned int* wflag = ws;                                            // [0]
    unsigned long long* wdata =
        reinterpret_cast<unsigned long long*>(reinterpret_cast<char*>(ws) + 16);

    if (blockIdx.x == 0) {
        build_coeffs(theta, sU, sOut, sCis, sC);
        // Publish: data as agent-scope relaxed atomics, then release the flag.
        if (tid < 26) {
            union { float2 f; unsigned long long u; } cv;
            cv.f = sC[tid];
            __hip_atomic_store(&wdata[tid], cv.u, __ATOMIC_RELAXED,
                               __HIP_MEMORY_SCOPE_AGENT);
        }
        __syncthreads();
        if (tid == 0)
            __hip_atomic_store(wflag, FLAG_MAGIC, __ATOMIC_RELEASE,
                               __HIP_MEMORY_SCOPE_AGENT);
    } else {
        if (tid == 0) {
            int ok = 0;
            for (int it = 0; it < (1 << 20); ++it) {
                if (__hip_atomic_load(wflag, __ATOMIC_ACQUIRE,
                                      __HIP_MEMORY_SCOPE_AGENT) == FLAG_MAGIC) {
                    ok = 1; break;
                }
                __builtin_amdgcn_s_sleep(2);
            }
            sState = ok;
        }
        __syncthreads();
        if (sState) {
            if (tid < 26) {
                union { float2 f; unsigned long long u; } cv;
                cv.u = __hip_atomic_load(&wdata[tid], __ATOMIC_RELAXED,
                                         __HIP_MEMORY_SCOPE_AGENT);
                sC[tid] = cv.f;
            }
            __syncthreads();
        } else {
            build_coeffs(theta, sU, sOut, sCis, sC);   // safe fallback
        }
    }

    // ---- coefficients -> wave-uniform registers ----
    v2f AB[25];
    const float4* cg = reinterpret_cast<const float4*>(sC);
#pragma unroll
    for (int q = 0; q < 13; ++q) {
        const float4 vv = cg[q];
        const int k0 = 2 * q;
        { v2f e; e.x = rfl(vv.x); e.y = rfl(vv.y); AB[k0] = e; }
        if (k0 + 1 < 25) { v2f e; e.x = rfl(vv.z); e.y = rfl(vv.w); AB[k0 + 1] = e; }
    }

    // ---- main: 8 samples/thread ----
    if (full) {
        float4 o0, o1;
        o0.x = evalSeries(tv0.x, AB);
        o0.y = evalSeries(tv0.y, AB);
        o0.z = evalSeries(tv0.z, AB);
        o0.w = evalSeries(tv0.w, AB);
        o1.x = evalSeries(tv1.x, AB);
        o1.y = evalSeries(tv1.y, AB);
        o1.z = evalSeries(tv1.z, AB);
        o1.w = evalSeries(tv1.w, AB);
        *reinterpret_cast<float4*>(out + base)     = o0;
        *reinterpret_cast<float4*>(out + base + 4) = o1;
    } else {
        for (int i = 0; i < SAMPLES_PER_THREAD; ++i)
            if (base + i < n) out[base + i] = evalSeries(t[base + i], AB);
    }
}

extern "C" void kernel_launch(void* const* d_in, const int* in_sizes, int n_in,
                              void* d_out, int out_size, void* d_ws, size_t ws_size,
                              hipStream_t stream)
{
    const float* t     = (const float*)d_in[0];
    const float* theta = (const float*)d_in[1];
    float* out         = (float*)d_out;
    const int n = in_sizes[0];

    const int per_block = 256 * SAMPLES_PER_THREAD;
    const int blocks = (n + per_block - 1) / per_block;
    qb_fused<<<blocks, 256, 0, stream>>>(t, theta, out, n,
                                         (unsigned int*)d_ws);
}

// Round 7
// 69.305 us; speedup vs baseline: 1.5128x; 1.5128x over previous
//
#include <hip/hip_runtime.h>
#include <math.h>

#ifndef M_PI
#define M_PI 3.14159265358979323846
#endif

typedef float v2f __attribute__((ext_vector_type(2)));

// 25 harmonics (k=0..24) of out(theta), theta = pi*t/2, as float2 {a_k, b_k};
// entry 25 is zero padding so main can read 13 aligned float4s.
__device__ __align__(16) float2 g_coef[26];

__device__ __forceinline__ float rfl(float x)
{
    return __int_as_float(__builtin_amdgcn_readfirstlane(__float_as_int(x)));
}

// Real RY butterfly on bit with stride ST: (a,b) -> (c*a - s*b, s*a + c*b)
template <int ST>
__device__ __forceinline__ void rotF(float c, float s, float (&vr)[8], float (&vi)[8])
{
#pragma unroll
    for (int k = 0; k < 8; ++k) {
        if (k & ST) continue;
        const int k1 = k + ST;
        const float ar = vr[k],  ai = vi[k];
        const float br = vr[k1], bi = vi[k1];
        vr[k]  = c * ar - s * br;  vi[k]  = c * ai - s * bi;
        vr[k1] = s * ar + c * br;  vi[k1] = s * ai + c * bi;
    }
}

// ---------------------------------------------------------------------------
// Prep (1 block, 64 threads = 1 wave):
//  1) lanes 0..23 build the three 8x8 ansatz-layer matrices into LDS
//  2) every lane j evaluates the circuit at theta_j = 2*pi*j/64 -> v_j,
//     caching cis(theta_j) in LDS
//  3) lanes 0..24: trig-free 64-point DFT (index (k*j)&63 into the cis table)
// Exact: out(theta) is a trig polynomial of degree 24 < 32 = Nyquist.
// ---------------------------------------------------------------------------
__global__ void qb_prep(const float* __restrict__ theta)
{
    __shared__ float2 sU[192];    // [layer][row][col]
    __shared__ float  sOut[64];   // v_j
    __shared__ float2 sCis[64];   // {cos theta_j, sin theta_j}
    const int tid = threadIdx.x;

    // ---- 1) ansatz-layer matrices ----
    if (tid < 24) {
        const int l = tid >> 3;
        const int c = tid & 7;
        float re[8], im[8];
#pragma unroll
        for (int k = 0; k < 8; ++k) { re[k] = (k == c) ? 1.f : 0.f; im[k] = 0.f; }

#pragma unroll
        for (int q = 0; q < 3; ++q) {
            const int p  = 2 - q;
            const int st = 1 << p;
            const float a0 = theta[l * 9 + q * 3 + 0];
            const float a1 = theta[l * 9 + q * 3 + 1];
            const float a2 = theta[l * 9 + q * 3 + 2];
            float sz, cz, sx, cx, sz2, cz2;
            __sincosf(0.5f * a0, &sz,  &cz);
            __sincosf(0.5f * a1, &sx,  &cx);
            __sincosf(0.5f * a2, &sz2, &cz2);
#pragma unroll
            for (int k = 0; k < 8; ++k) {          // RZ(a0)
                const float s = ((k >> p) & 1) ? sz : -sz;
                const float r0 = re[k] * cz - im[k] * s;
                const float i0 = re[k] * s  + im[k] * cz;
                re[k] = r0; im[k] = i0;
            }
#pragma unroll
            for (int k = 0; k < 8; ++k) {          // RX(a1)
                if ((k >> p) & 1) continue;
                const int k1 = k + st;
                const float r0 =  cx * re[k]  + sx * im[k1];
                const float i0 =  cx * im[k]  - sx * re[k1];
                const float r1 =  sx * im[k]  + cx * re[k1];
                const float i1 = -sx * re[k]  + cx * im[k1];
                re[k] = r0; im[k] = i0; re[k1] = r1; im[k1] = i1;
            }
#pragma unroll
            for (int k = 0; k < 8; ++k) {          // RZ(a2)
                const float s = ((k >> p) & 1) ? sz2 : -sz2;
                const float r0 = re[k] * cz2 - im[k] * s;
                const float i0 = re[k] * s   + im[k] * cz2;
                re[k] = r0; im[k] = i0;
            }
        }
        // CNOT(0,1), CNOT(1,2), CNOT(2,0)
#define SWP(a, b) { float tr = re[a]; re[a] = re[b]; re[b] = tr; \
                    float ti = im[a]; im[a] = im[b]; im[b] = ti; }
        SWP(4, 6); SWP(5, 7);
        SWP(2, 3); SWP(6, 7);
        SWP(1, 5); SWP(3, 7);
#undef SWP
#pragma unroll
        for (int r = 0; r < 8; ++r)
            sU[l * 64 + r * 8 + c] = make_float2(re[r], im[r]);
    }
    __syncthreads();

    // ---- 2) circuit eval at theta_j, j = lane ----
    {
        const float w0 = (float)(M_PI / 32.0);
        float c1, s1;
        __sincosf(w0 * (float)tid, &s1, &c1);
        const float c2 = c1 * c1 - s1 * s1, s2 = 2.f * s1 * c1;
        const float c3 = c2 * c1 - s2 * s1, s3 = s2 * c1 + c2 * s1;

        float wr[8], wi[8];
#pragma unroll
        for (int r = 0; r < 8; ++r) { const float2 u = sU[r * 8]; wr[r] = u.x; wi[r] = u.y; }
        rotF<4>(c1, s1, wr, wi);
        rotF<2>(c2, s2, wr, wi);
        rotF<1>(c3, s3, wr, wi);

        float xr[8], xi[8];
#pragma unroll
        for (int r = 0; r < 8; ++r) {
            float zr = 0.f, zi = 0.f;
#pragma unroll
            for (int cc = 0; cc < 8; ++cc) {
                const float2 u = sU[64 + r * 8 + cc];
                zr += u.x * wr[cc] - u.y * wi[cc];
                zi += u.x * wi[cc] + u.y * wr[cc];
            }
            xr[r] = zr; xi[r] = zi;
        }
        rotF<4>(c1, s1, xr, xi);
        rotF<2>(c2, s2, xr, xi);
        rotF<1>(c3, s3, xr, xi);

        float v = 0.f;
#pragma unroll
        for (int r = 0; r < 8; ++r) {
            float zr = 0.f, zi = 0.f;
#pragma unroll
            for (int cc = 0; cc < 8; ++cc) {
                const float2 u = sU[128 + r * 8 + cc];
                zr += u.x * xr[cc] - u.y * xi[cc];
                zi += u.x * xi[cc] + u.y * xr[cc];
            }
            const float m = zr * zr + zi * zi;
            v += (r < 4) ? m : -m;
        }
        sOut[tid] = v;
        sCis[tid] = make_float2(c1, s1);
    }
    __syncthreads();

    // ---- 3) trig-free DFT: lane k sums v_j * cis(k * theta_j) ----
    if (tid < 26) {
        if (tid == 25) {
            g_coef[25] = make_float2(0.f, 0.f);
        } else {
            float sa = 0.f, sb = 0.f;
#pragma unroll
            for (int j = 0; j < 64; ++j) {
                const float  vj = sOut[j];
                const float2 w  = sCis[(tid * j) & 63];
                sa += vj * w.x;
                sb += vj * w.y;
            }
            const float sc = (tid == 0) ? (1.f / 64.f) : (2.f / 64.f);
            g_coef[tid] = make_float2(sa * sc, (tid == 0) ? 0.f : sb * sc);
        }
    }
}

// ---------------------------------------------------------------------------
// Main: 1 thread = 4 samples (one unit-stride float4 load + float4 store).
// 8192 waves -> 32 waves/CU (max occupancy). Packed-FP32 Chebyshev
// recurrence over the (cos,sin) pair per harmonic.
// ---------------------------------------------------------------------------
__device__ __forceinline__ float evalSeries(float tval, const v2f (&AB)[25])
{
    const float th = 1.5707963267948966f * tval;   // theta = pi*t/2
    float s1, c1;
    __sincosf(th, &s1, &c1);
    const v2f tc = { 2.f * c1, 2.f * c1 };
    v2f pp = { 1.f, 0.f };        // cis(0)
    v2f pc = { c1, s1 };          // cis(theta)
    v2f acc = AB[0] * pp + AB[1] * pc;
#pragma unroll
    for (int k = 2; k <= 24; ++k) {
        const v2f pn = tc * pc - pp;   // cis(k*theta) via Chebyshev
        pp = pc; pc = pn;
        acc = AB[k] * pn + acc;
    }
    return acc.x + acc.y;
}

__global__ __launch_bounds__(256) void qb_main(const float* __restrict__ t,
                                               float* __restrict__ out, int n)
{
    // Coefficients -> wave-uniform registers (readfirstlane -> SGPRs).
    v2f AB[25];
    const float4* cg = reinterpret_cast<const float4*>(g_coef);
#pragma unroll
    for (int q = 0; q < 13; ++q) {
        const float4 vv = cg[q];
        const int k0 = 2 * q;
        { v2f e; e.x = rfl(vv.x); e.y = rfl(vv.y); AB[k0] = e; }
        if (k0 + 1 < 25) { v2f e; e.x = rfl(vv.z); e.y = rfl(vv.w); AB[k0 + 1] = e; }
    }

    const int base = (blockIdx.x * 256 + threadIdx.x) * 4;
    if (base + 3 < n) {
        const float4 tv = *reinterpret_cast<const float4*>(t + base);
        float4 ov;
        ov.x = evalSeries(tv.x, AB);
        ov.y = evalSeries(tv.y, AB);
        ov.z = evalSeries(tv.z, AB);
        ov.w = evalSeries(tv.w, AB);
        *reinterpret_cast<float4*>(out + base) = ov;
    } else {
        for (int i = 0; i < 4; ++i)
            if (base + i < n) out[base + i] = evalSeries(t[base + i], AB);
    }
}

extern "C" void kernel_launch(void* const* d_in, const int* in_sizes, int n_in,
                              void* d_out, int out_size, void* d_ws, size_t ws_size,
                              hipStream_t stream)
{
    const float* t     = (const float*)d_in[0];
    const float* theta = (const float*)d_in[1];
    float* out         = (float*)d_out;
    const int n = in_sizes[0];

    qb_prep<<<1, 64, 0, stream>>>(theta);
    const int per_block = 256 * 4;
    const int blocks = (n + per_block - 1) / per_block;
    qb_main<<<blocks, 256, 0, stream>>>(t, out, n);
}